// Round 1
// baseline (2026.800 us; speedup 1.0000x reference)
//
#include <hip/hip_runtime.h>

// Problem constants (from reference)
#define N_ENC 500000
#define N_PAT 100000
#define D 64
#define HID 128
#define NE 1000000

// Workspace layout (float units). Zeroed region first so one memset covers it.
#define OFF_AGG_ENC 0               // N_ENC*64 = 32,000,000
#define OFF_CNT_ENC 32000000        // 500,000
#define OFF_AGG_PAT 32500000        // 6,400,000
#define OFF_CNT_PAT 38900000        // 100,000
#define OFF_SUM2    39000000        // 500,000
#define ZERO_FLOATS 39500000        // 158 MB zeroed
#define OFF_SPAT    39500000        // 100,000
#define OFF_WLT_PE1 39600000        // 8192 (WlT_pe1 [128][64])
#define OFF_WRT_PE1 39608192        // 8192
#define OFF_WLT_EP1 39616384        // 8192
#define OFF_WRT_EP1 39624576        // 8192
#define OFF_WL2C    39632768        // 128
#define OFF_WR2C    39632896        // 128
#define OFF_C0      39633024        // 1
// total ~158.6 MB of ws

// Prep: transpose the four 64x128 layer-1 weights into [j][k] rows (so the
// transform kernel's weight reads are wave-uniform scalar loads), and collapse
// layer-2: wl2c = Wl_pe2@Wc, wr2c = Wr_pe2@Wc, c0 = b_pe2.Wc + bc.
__global__ __launch_bounds__(256) void prep_kernel(
    const float* __restrict__ Wl_pe1, const float* __restrict__ Wr_pe1,
    const float* __restrict__ Wl_ep1, const float* __restrict__ Wr_ep1,
    const float* __restrict__ Wl_pe2, const float* __restrict__ Wr_pe2,
    const float* __restrict__ b_pe2, const float* __restrict__ Wc,
    const float* __restrict__ bc, float* __restrict__ ws)
{
    int t = blockIdx.x * blockDim.x + threadIdx.x;
    const int total = 4 * D * HID;  // 32768
    for (int i = t; i < total; i += gridDim.x * blockDim.x) {
        int m = i >> 13;            // which matrix (0..3)
        int r = i & 8191;           // j*64+k
        int j = r >> 6;
        int k = r & 63;
        const float* src = (m == 0) ? Wl_pe1 : (m == 1) ? Wr_pe1
                         : (m == 2) ? Wl_ep1 : Wr_ep1;
        ws[OFF_WLT_PE1 + m * 8192 + r] = src[k * HID + j];
    }
    if (blockIdx.x == 0) {
        int tid = threadIdx.x;
        if (tid < HID) {
            float s1 = 0.f, s2 = 0.f;
            for (int j = 0; j < HID; j++) {
                float wc = Wc[j];
                s1 += Wl_pe2[tid * HID + j] * wc;
                s2 += Wr_pe2[tid * HID + j] * wc;
            }
            ws[OFF_WL2C + tid] = s1;
            ws[OFF_WR2C + tid] = s2;
            if (tid == 0) {
                float c0 = bc[0];
                for (int j = 0; j < HID; j++) c0 += b_pe2[j] * Wc[j];
                ws[OFF_C0] = c0;
            }
        }
    }
}

// Layer-1 aggregation scatter: 64 lanes per edge, one float per lane.
// Gathered source row is coalesced (256B/edge); atomics land on 64
// consecutive floats of the destination row.
__global__ __launch_bounds__(256) void scatter_kernel(
    const float* __restrict__ xsrc, const int* __restrict__ src,
    const int* __restrict__ dst, float* __restrict__ agg,
    float* __restrict__ cnt, int E)
{
    long long t = (long long)blockIdx.x * blockDim.x + threadIdx.x;
    int e = (int)(t >> 6);
    int lane = (int)(t & 63);
    if (e >= E) return;
    int s = src[e];
    int d = dst[e];
    float v = xsrc[(size_t)s * D + lane];
    atomicAdd(&agg[(size_t)d * D + lane], v);
    if (lane == 0) atomicAdd(&cnt[d], 1.0f);
}

// Layer-2 scalar aggregation: sum2[dst] += s_pat[src].
__global__ __launch_bounds__(256) void scatter_scalar_kernel(
    const float* __restrict__ sval, const int* __restrict__ src,
    const int* __restrict__ dst, float* __restrict__ sum2, int E)
{
    int e = blockIdx.x * blockDim.x + threadIdx.x;
    if (e < E) atomicAdd(&sum2[dst[e]], sval[src[e]]);
}

// Fused node transform: z = (agg/cnt)@Wl + x@Wr + b ; out = sum_j relu(z_j)*cvec_j
// (+ optional sum2/cnt + c0 for the encounter/logit path).
// Thread-per-node: node inputs live in 128 VGPRs; weights are read with
// wave-uniform indices -> compiler emits s_load (scalar pipe), no LDS needed.
__global__ __launch_bounds__(256) void transform_kernel(
    const float* __restrict__ agg_sum, const float* __restrict__ cnt,
    const float* __restrict__ x_in,
    const float* __restrict__ WlT,   // [128][64], row j = column j of Wl
    const float* __restrict__ WrT,   // [128][64]
    const float* __restrict__ bias,  // [128]
    const float* __restrict__ cvec,  // [128] (wl2c or wr2c)
    const float* __restrict__ sum2,  // [N] or nullptr
    const float* __restrict__ c0p,   // [1] or nullptr
    float* __restrict__ out, int N, int add_extra)
{
    int n = blockIdx.x * blockDim.x + threadIdx.x;
    if (n >= N) return;
    float invc = 1.0f / fmaxf(cnt[n], 1.0f);
    const float4* ap = (const float4*)(agg_sum + (size_t)n * D);
    const float4* xp = (const float4*)(x_in + (size_t)n * D);
    float4 a[16], x[16];
#pragma unroll
    for (int i = 0; i < 16; i++) { a[i] = ap[i]; x[i] = xp[i]; }
#pragma unroll
    for (int i = 0; i < 16; i++) {
        a[i].x *= invc; a[i].y *= invc; a[i].z *= invc; a[i].w *= invc;
    }
    float acc = 0.f;
    for (int j = 0; j < HID; j++) {
        const float4* wl = (const float4*)(WlT + j * D);
        const float4* wr = (const float4*)(WrT + j * D);
        // 8 independent FMA chains to keep dep-latency off the critical path
        float4 z1 = make_float4(0.f, 0.f, 0.f, 0.f);
        float4 z2 = make_float4(0.f, 0.f, 0.f, 0.f);
#pragma unroll
        for (int kk = 0; kk < 16; kk++) {
            float4 w1 = wl[kk];
            float4 w2 = wr[kk];
            z1.x = fmaf(a[kk].x, w1.x, z1.x);
            z1.y = fmaf(a[kk].y, w1.y, z1.y);
            z1.z = fmaf(a[kk].z, w1.z, z1.z);
            z1.w = fmaf(a[kk].w, w1.w, z1.w);
            z2.x = fmaf(x[kk].x, w2.x, z2.x);
            z2.y = fmaf(x[kk].y, w2.y, z2.y);
            z2.z = fmaf(x[kk].z, w2.z, z2.z);
            z2.w = fmaf(x[kk].w, w2.w, z2.w);
        }
        float z = bias[j] + ((z1.x + z1.y) + (z1.z + z1.w))
                          + ((z2.x + z2.y) + (z2.z + z2.w));
        z = fmaxf(z, 0.f);
        acc = fmaf(z, cvec[j], acc);
    }
    if (add_extra) acc += sum2[n] * invc + c0p[0];
    out[n] = acc;
}

extern "C" void kernel_launch(void* const* d_in, const int* in_sizes, int n_in,
                              void* d_out, int out_size, void* d_ws, size_t ws_size,
                              hipStream_t stream)
{
    const float* x_enc  = (const float*)d_in[0];
    const float* x_pat  = (const float*)d_in[1];
    const int*   src_pe = (const int*)d_in[2];
    const int*   dst_pe = (const int*)d_in[3];
    const int*   src_ep = (const int*)d_in[4];
    const int*   dst_ep = (const int*)d_in[5];
    const float* Wl_pe1 = (const float*)d_in[6];
    const float* Wr_pe1 = (const float*)d_in[7];
    const float* b_pe1  = (const float*)d_in[8];
    const float* Wl_ep1 = (const float*)d_in[9];
    const float* Wr_ep1 = (const float*)d_in[10];
    const float* b_ep1  = (const float*)d_in[11];
    const float* Wl_pe2 = (const float*)d_in[12];
    const float* Wr_pe2 = (const float*)d_in[13];
    const float* b_pe2  = (const float*)d_in[14];
    // d_in[15..17] = Wl_ep2/Wr_ep2/b_ep2: unused by the reference
    const float* Wc = (const float*)d_in[18];
    const float* bc = (const float*)d_in[19];

    float* ws  = (float*)d_ws;
    float* out = (float*)d_out;

    // zero accumulation buffers (~158 MB)
    hipMemsetAsync(d_ws, 0, (size_t)ZERO_FLOATS * sizeof(float), stream);

    prep_kernel<<<32, 256, 0, stream>>>(Wl_pe1, Wr_pe1, Wl_ep1, Wr_ep1,
                                        Wl_pe2, Wr_pe2, b_pe2, Wc, bc, ws);

    // layer-1 mean-agg scatters (64 lanes/edge)
    int sblocks = (int)(((long long)NE * 64 + 255) / 256);
    scatter_kernel<<<sblocks, 256, 0, stream>>>(
        x_enc, src_ep, dst_ep, ws + OFF_AGG_PAT, ws + OFF_CNT_PAT, NE);
    scatter_kernel<<<sblocks, 256, 0, stream>>>(
        x_pat, src_pe, dst_pe, ws + OFF_AGG_ENC, ws + OFF_CNT_ENC, NE);

    // patient transform -> s_pat (scalar per patient)
    transform_kernel<<<(N_PAT + 255) / 256, 256, 0, stream>>>(
        ws + OFF_AGG_PAT, ws + OFF_CNT_PAT, x_pat,
        ws + OFF_WLT_EP1, ws + OFF_WRT_EP1, b_ep1, ws + OFF_WL2C,
        nullptr, nullptr, ws + OFF_SPAT, N_PAT, 0);

    // layer-2 scalar aggregation
    scatter_scalar_kernel<<<(NE + 255) / 256, 256, 0, stream>>>(
        ws + OFF_SPAT, src_pe, dst_pe, ws + OFF_SUM2, NE);

    // encounter transform -> logits
    transform_kernel<<<(N_ENC + 255) / 256, 256, 0, stream>>>(
        ws + OFF_AGG_ENC, ws + OFF_CNT_ENC, x_enc,
        ws + OFF_WLT_PE1, ws + OFF_WRT_PE1, b_pe1, ws + OFF_WR2C,
        ws + OFF_SUM2, ws + OFF_C0, out, N_ENC, 1);
}

// Round 2
// 914.022 us; speedup vs baseline: 2.2175x; 2.2175x over previous
//
#include <hip/hip_runtime.h>

// Problem constants (from reference)
#define N_ENC 500000
#define N_PAT 100000
#define D 64
#define HID 128
#define NE 1000000

typedef unsigned short ushort_t;
typedef unsigned int uint_t;
typedef __attribute__((ext_vector_type(8))) short bfrag8;   // 8 x bf16 (4 VGPRs)
typedef __attribute__((ext_vector_type(4))) float f32x4;

// Workspace layout (float units). Zeroed region first so one memset covers it.
#define OFF_AGG_ENC 0               // N_ENC*64 = 32,000,000
#define OFF_CNT_ENC 32000000        // 500,000
#define OFF_AGG_PAT 32500000        // 6,400,000
#define OFF_CNT_PAT 38900000        // 100,000
#define OFF_SUM2    39000000        // 500,000
#define ZERO_FLOATS 39500000        // 158 MB zeroed
#define OFF_SPAT    39500000        // 100,000
#define OFF_FRAGS   39600000        // 4 matrices * 8192 ushort = 32768 ushort = 16384 floats
#define OFF_WL2C    39616384        // 128
#define OFF_WR2C    39616512        // 128
#define OFF_C0      39616640        // 1

__device__ inline ushort_t f2bf(float x) {
    // round-to-nearest-even f32 -> bf16
    uint_t u = __float_as_uint(x);
    u += 0x7fffu + ((u >> 16) & 1u);
    return (ushort_t)(u >> 16);
}

// Prep:
//  (a) pack the four 64x128 layer-1 weights into bf16 MFMA B-fragment layout:
//      for matrix m, frag (jt,kt), lane l, elem jj:
//        value = W[k][j], k = kt*32 + (l>>4)*8 + jj, j = jt*16 + (l&15)
//      stored at frags[m*8192 + ((jt*2+kt)*64 + l)*8 + jj]
//  (b) collapse layer 2: wl2c = Wl_pe2@Wc, wr2c = Wr_pe2@Wc, c0 = b_pe2.Wc + bc
__global__ __launch_bounds__(256) void prep_kernel(
    const float* __restrict__ Wl_pe1, const float* __restrict__ Wr_pe1,
    const float* __restrict__ Wl_ep1, const float* __restrict__ Wr_ep1,
    const float* __restrict__ Wl_pe2, const float* __restrict__ Wr_pe2,
    const float* __restrict__ b_pe2, const float* __restrict__ Wc,
    const float* __restrict__ bc, float* __restrict__ ws)
{
    int t = blockIdx.x * blockDim.x + threadIdx.x;
    const int total = 4 * 8192;
    ushort_t* fr = (ushort_t*)(ws + OFF_FRAGS);
    for (int i = t; i < total; i += gridDim.x * blockDim.x) {
        int mtx = i >> 13;
        int r = i & 8191;
        int jj = r & 7;
        int l = (r >> 3) & 63;
        int ft = r >> 9;          // 0..15 = jt*2+kt
        int kt = ft & 1;
        int jt = ft >> 1;
        int k = kt * 32 + (l >> 4) * 8 + jj;
        int j = jt * 16 + (l & 15);
        const float* W = (mtx == 0) ? Wl_pe1 : (mtx == 1) ? Wr_pe1
                       : (mtx == 2) ? Wl_ep1 : Wr_ep1;
        fr[i] = f2bf(W[k * HID + j]);
    }
    if (blockIdx.x == 0) {
        int tid = threadIdx.x;
        if (tid < HID) {
            float s1 = 0.f, s2 = 0.f;
            for (int j = 0; j < HID; j++) {
                float wc = Wc[j];
                s1 += Wl_pe2[tid * HID + j] * wc;
                s2 += Wr_pe2[tid * HID + j] * wc;
            }
            ws[OFF_WL2C + tid] = s1;
            ws[OFF_WR2C + tid] = s2;
            if (tid == 0) {
                float c0 = bc[0];
                for (int j = 0; j < HID; j++) c0 += b_pe2[j] * Wc[j];
                ws[OFF_C0] = c0;
            }
        }
    }
}

// Layer-1 aggregation scatter: 64 lanes per edge, one float per lane.
__global__ __launch_bounds__(256) void scatter_kernel(
    const float* __restrict__ xsrc, const int* __restrict__ src,
    const int* __restrict__ dst, float* __restrict__ agg,
    float* __restrict__ cnt, int E)
{
    long long t = (long long)blockIdx.x * blockDim.x + threadIdx.x;
    int e = (int)(t >> 6);
    int lane = (int)(t & 63);
    if (e >= E) return;
    int s = src[e];
    int d = dst[e];
    float v = xsrc[(size_t)s * D + lane];
    atomicAdd(&agg[(size_t)d * D + lane], v);
    if (lane == 0) atomicAdd(&cnt[d], 1.0f);
}

// Layer-2 scalar aggregation: sum2[dst] += s_pat[src].
__global__ __launch_bounds__(256) void scatter_scalar_kernel(
    const float* __restrict__ sval, const int* __restrict__ src,
    const int* __restrict__ dst, float* __restrict__ sum2, int E)
{
    int e = blockIdx.x * blockDim.x + threadIdx.x;
    if (e < E) atomicAdd(&sum2[dst[e]], sval[src[e]]);
}

__device__ inline bfrag8 ld_cvt8(const float* p, float s) {
    f32x4 v0 = *(const f32x4*)p;
    f32x4 v1 = *(const f32x4*)(p + 4);
    bfrag8 r;
    r[0] = (short)f2bf(v0[0] * s); r[1] = (short)f2bf(v0[1] * s);
    r[2] = (short)f2bf(v0[2] * s); r[3] = (short)f2bf(v0[3] * s);
    r[4] = (short)f2bf(v1[0] * s); r[5] = (short)f2bf(v1[1] * s);
    r[6] = (short)f2bf(v1[2] * s); r[7] = (short)f2bf(v1[3] * s);
    return r;
}

// MFMA node transform. One wave = 16 nodes.
//   z[n][j] = (agg[n]/cnt[n]) @ Wl + x[n] @ Wr + bias   (K=64, J=128, bf16 MFMA)
//   out[n]  = sum_j relu(z[n][j]) * cvec[j]  (+ sum2[n]/cnt[n] + c0 if add_extra)
// A-frag (16x16x32): lane holds A[m=lane&15][k=(lane>>4)*8+jj]
// B-frag: lane holds B[k=(lane>>4)*8+jj][n=lane&15]  (pre-packed by prep)
// C/D:   col=lane&15, row=(lane>>4)*4+reg             (m89/m91-verified)
__global__ __launch_bounds__(256) void transform_mfma_kernel(
    const float* __restrict__ agg, const float* __restrict__ cnt,
    const float* __restrict__ x_in,
    const ushort_t* __restrict__ fragWl, const ushort_t* __restrict__ fragWr,
    const float* __restrict__ bias, const float* __restrict__ cvec,
    const float* __restrict__ sum2, const float* __restrict__ c0p,
    float* __restrict__ out, int nwaves, int add_extra)
{
    int wid = blockIdx.x * 4 + (threadIdx.x >> 6);
    if (wid >= nwaves) return;
    int l = threadIdx.x & 63;
    int m = l & 15;          // node within tile (A rows / C cols-lane)
    int q = l >> 4;          // quad
    int nb = wid * 16;
    int row = nb + m;

    float invc = 1.0f / fmaxf(cnt[row], 1.0f);
    const float* ap = agg + (size_t)row * D;
    const float* xp = x_in + (size_t)row * D;
    bfrag8 a0 = ld_cvt8(ap + q * 8, invc);
    bfrag8 a1 = ld_cvt8(ap + 32 + q * 8, invc);
    bfrag8 x0 = ld_cvt8(xp + q * 8, 1.0f);
    bfrag8 x1 = ld_cvt8(xp + 32 + q * 8, 1.0f);

    // per-lane bias/cvec for col m at each jt
    float bias_v[8], cvec_v[8];
#pragma unroll
    for (int jt = 0; jt < 8; jt++) {
        bias_v[jt] = bias[jt * 16 + m];
        cvec_v[jt] = cvec[jt * 16 + m];
    }

    float p0 = 0.f, p1 = 0.f, p2 = 0.f, p3 = 0.f;
#pragma unroll
    for (int jt = 0; jt < 8; jt++) {
        const bfrag8* bl0 = (const bfrag8*)(fragWl + ((size_t)(jt * 2 + 0) * 64 + l) * 8);
        const bfrag8* bl1 = (const bfrag8*)(fragWl + ((size_t)(jt * 2 + 1) * 64 + l) * 8);
        const bfrag8* br0 = (const bfrag8*)(fragWr + ((size_t)(jt * 2 + 0) * 64 + l) * 8);
        const bfrag8* br1 = (const bfrag8*)(fragWr + ((size_t)(jt * 2 + 1) * 64 + l) * 8);
        f32x4 acc = {0.f, 0.f, 0.f, 0.f};
        acc = __builtin_amdgcn_mfma_f32_16x16x32_bf16(a0, *bl0, acc, 0, 0, 0);
        acc = __builtin_amdgcn_mfma_f32_16x16x32_bf16(a1, *bl1, acc, 0, 0, 0);
        acc = __builtin_amdgcn_mfma_f32_16x16x32_bf16(x0, *br0, acc, 0, 0, 0);
        acc = __builtin_amdgcn_mfma_f32_16x16x32_bf16(x1, *br1, acc, 0, 0, 0);
        float bj = bias_v[jt], cj = cvec_v[jt];
        p0 += fmaxf(acc[0] + bj, 0.f) * cj;
        p1 += fmaxf(acc[1] + bj, 0.f) * cj;
        p2 += fmaxf(acc[2] + bj, 0.f) * cj;
        p3 += fmaxf(acc[3] + bj, 0.f) * cj;
    }
    // sum over the 16 lanes of each quad (cols 0..15, same rows)
#pragma unroll
    for (int off = 1; off < 16; off <<= 1) {
        p0 += __shfl_xor(p0, off, 16);
        p1 += __shfl_xor(p1, off, 16);
        p2 += __shfl_xor(p2, off, 16);
        p3 += __shfl_xor(p3, off, 16);
    }
    if (m == 0) {
        int base = nb + q * 4;   // this quad's 4 nodes
        f32x4 o;
        o[0] = p0; o[1] = p1; o[2] = p2; o[3] = p3;
        if (add_extra) {
            float c0 = c0p[0];
#pragma unroll
            for (int r = 0; r < 4; r++) {
                int node = base + r;
                float ic = 1.0f / fmaxf(cnt[node], 1.0f);
                o[r] += sum2[node] * ic + c0;
            }
        }
        *(f32x4*)(out + base) = o;
    }
}

extern "C" void kernel_launch(void* const* d_in, const int* in_sizes, int n_in,
                              void* d_out, int out_size, void* d_ws, size_t ws_size,
                              hipStream_t stream)
{
    const float* x_enc  = (const float*)d_in[0];
    const float* x_pat  = (const float*)d_in[1];
    const int*   src_pe = (const int*)d_in[2];
    const int*   dst_pe = (const int*)d_in[3];
    const int*   src_ep = (const int*)d_in[4];
    const int*   dst_ep = (const int*)d_in[5];
    const float* Wl_pe1 = (const float*)d_in[6];
    const float* Wr_pe1 = (const float*)d_in[7];
    const float* b_pe1  = (const float*)d_in[8];
    const float* Wl_ep1 = (const float*)d_in[9];
    const float* Wr_ep1 = (const float*)d_in[10];
    const float* b_ep1  = (const float*)d_in[11];
    const float* Wl_pe2 = (const float*)d_in[12];
    const float* Wr_pe2 = (const float*)d_in[13];
    const float* b_pe2  = (const float*)d_in[14];
    const float* Wc = (const float*)d_in[18];
    const float* bc = (const float*)d_in[19];

    float* ws  = (float*)d_ws;
    float* out = (float*)d_out;

    hipMemsetAsync(d_ws, 0, (size_t)ZERO_FLOATS * sizeof(float), stream);

    prep_kernel<<<128, 256, 0, stream>>>(Wl_pe1, Wr_pe1, Wl_ep1, Wr_ep1,
                                         Wl_pe2, Wr_pe2, b_pe2, Wc, bc, ws);

    int sblocks = (int)(((long long)NE * 64 + 255) / 256);
    scatter_kernel<<<sblocks, 256, 0, stream>>>(
        x_enc, src_ep, dst_ep, ws + OFF_AGG_PAT, ws + OFF_CNT_PAT, NE);
    scatter_kernel<<<sblocks, 256, 0, stream>>>(
        x_pat, src_pe, dst_pe, ws + OFF_AGG_ENC, ws + OFF_CNT_ENC, NE);

    const ushort_t* frags = (const ushort_t*)(ws + OFF_FRAGS);

    // patient transform -> s_pat (scalar per patient); Wl_ep1/Wr_ep1, cvec=wl2c
    int pat_waves = N_PAT / 16;   // 6250
    transform_mfma_kernel<<<(pat_waves + 3) / 4, 256, 0, stream>>>(
        ws + OFF_AGG_PAT, ws + OFF_CNT_PAT, x_pat,
        frags + 2 * 8192, frags + 3 * 8192, b_ep1, ws + OFF_WL2C,
        nullptr, nullptr, ws + OFF_SPAT, pat_waves, 0);

    // layer-2 scalar aggregation
    scatter_scalar_kernel<<<(NE + 255) / 256, 256, 0, stream>>>(
        ws + OFF_SPAT, src_pe, dst_pe, ws + OFF_SUM2, NE);

    // encounter transform -> logits; Wl_pe1/Wr_pe1, cvec=wr2c
    int enc_waves = N_ENC / 16;   // 31250
    transform_mfma_kernel<<<(enc_waves + 3) / 4, 256, 0, stream>>>(
        ws + OFF_AGG_ENC, ws + OFF_CNT_ENC, x_enc,
        frags + 0 * 8192, frags + 1 * 8192, b_pe1, ws + OFF_WR2C,
        ws + OFF_SUM2, ws + OFF_C0, out, enc_waves, 1);
}

// Round 3
// 653.968 us; speedup vs baseline: 3.0992x; 1.3977x over previous
//
#include <hip/hip_runtime.h>
#include <hip/hip_bf16.h>

// Problem constants (from reference)
#define N_ENC 500000
#define N_PAT 100000
#define D 64
#define HID 128
#define NE 1000000

typedef unsigned short ushort_t;
typedef unsigned int uint_t;
typedef __attribute__((ext_vector_type(8))) short bfrag8;   // 8 x bf16 (4 VGPRs)
typedef __attribute__((ext_vector_type(4))) float f32x4;

// Workspace layout (float units). Zeroed region first so one memset covers it.
// agg buffers are bf16 now (2 bytes/elem).
#define OFF_AGG_ENC 0               // 500,000*64 bf16 = 16,000,000 floats
#define OFF_AGG_PAT 16000000        // 100,000*64 bf16 = 3,200,000 floats
#define OFF_CNT_ENC 19200000        // 500,000
#define OFF_CNT_PAT 19700000        // 100,000
#define OFF_SUM2    19800000        // 500,000
#define ZERO_FLOATS 20300000        // 81.2 MB zeroed
#define OFF_SPAT    20300000        // 100,000
#define OFF_FRAGS   20400000        // 4 matrices * 8192 ushort = 16384 floats
#define OFF_WL2C    20416384        // 128
#define OFF_WR2C    20416512        // 128
#define OFF_C0      20416640        // 1

__device__ inline ushort_t f2bf(float x) {
    // round-to-nearest-even f32 -> bf16
    uint_t u = __float_as_uint(x);
    u += 0x7fffu + ((u >> 16) & 1u);
    return (ushort_t)(u >> 16);
}
__device__ inline float bf2f(ushort_t u) {
    return __uint_as_float(((uint_t)u) << 16);
}

// Packed bf16x2 atomic add: use HW global_atomic_pk_add_bf16 if the HIP
// overload exists (gfx90a+), else CAS fallback. SFINAE picks at compile time.
template <typename T>
__device__ inline auto pk_add(T* p, T v, int) -> decltype(unsafeAtomicAdd(p, v), void()) {
    unsafeAtomicAdd(p, v);
}
template <typename T>
__device__ inline void pk_add(T* p, T v, long) {
    uint_t* a = (uint_t*)p;
    uint_t uv;
    __builtin_memcpy(&uv, &v, 4);
    float addlo = bf2f((ushort_t)(uv & 0xffffu));
    float addhi = bf2f((ushort_t)(uv >> 16));
    uint_t old = *a, assumed;
    do {
        assumed = old;
        ushort_t nlo = f2bf(bf2f((ushort_t)(assumed & 0xffffu)) + addlo);
        ushort_t nhi = f2bf(bf2f((ushort_t)(assumed >> 16)) + addhi);
        old = atomicCAS(a, assumed, nlo | ((uint_t)nhi << 16));
    } while (old != assumed);
}

// Prep:
//  (a) pack the four 64x128 layer-1 weights into bf16 MFMA B-fragment layout:
//      frag (jt,kt), lane l, elem jj: value = W[k][j],
//        k = kt*32 + (l>>4)*8 + jj, j = jt*16 + (l&15)
//  (b) collapse layer 2: wl2c = Wl_pe2@Wc, wr2c = Wr_pe2@Wc, c0 = b_pe2.Wc + bc
__global__ __launch_bounds__(256) void prep_kernel(
    const float* __restrict__ Wl_pe1, const float* __restrict__ Wr_pe1,
    const float* __restrict__ Wl_ep1, const float* __restrict__ Wr_ep1,
    const float* __restrict__ Wl_pe2, const float* __restrict__ Wr_pe2,
    const float* __restrict__ b_pe2, const float* __restrict__ Wc,
    const float* __restrict__ bc, float* __restrict__ ws)
{
    int t = blockIdx.x * blockDim.x + threadIdx.x;
    const int total = 4 * 8192;
    ushort_t* fr = (ushort_t*)(ws + OFF_FRAGS);
    for (int i = t; i < total; i += gridDim.x * blockDim.x) {
        int mtx = i >> 13;
        int r = i & 8191;
        int jj = r & 7;
        int l = (r >> 3) & 63;
        int ft = r >> 9;          // 0..15 = jt*2+kt
        int kt = ft & 1;
        int jt = ft >> 1;
        int k = kt * 32 + (l >> 4) * 8 + jj;
        int j = jt * 16 + (l & 15);
        const float* W = (mtx == 0) ? Wl_pe1 : (mtx == 1) ? Wr_pe1
                       : (mtx == 2) ? Wl_ep1 : Wr_ep1;
        fr[i] = f2bf(W[k * HID + j]);
    }
    if (blockIdx.x == 0) {
        int tid = threadIdx.x;
        if (tid < HID) {
            float s1 = 0.f, s2 = 0.f;
            for (int j = 0; j < HID; j++) {
                float wc = Wc[j];
                s1 += Wl_pe2[tid * HID + j] * wc;
                s2 += Wr_pe2[tid * HID + j] * wc;
            }
            ws[OFF_WL2C + tid] = s1;
            ws[OFF_WR2C + tid] = s2;
            if (tid == 0) {
                float c0 = bc[0];
                for (int j = 0; j < HID; j++) c0 += b_pe2[j] * Wc[j];
                ws[OFF_C0] = c0;
            }
        }
    }
}

// Layer-1 aggregation scatter: 32 lanes per edge, one bf16x2 packed atomic per
// lane (halves atomic-op count vs f32 — the measured bottleneck).
__global__ __launch_bounds__(256) void scatter_kernel(
    const float* __restrict__ xsrc, const int* __restrict__ src,
    const int* __restrict__ dst, ushort_t* __restrict__ agg,
    float* __restrict__ cnt, int E)
{
    long long t = (long long)blockIdx.x * blockDim.x + threadIdx.x;
    int e = (int)(t >> 5);
    int pair = (int)(t & 31);
    if (e >= E) return;
    int s = src[e];
    int d = dst[e];
    float2 v = *(const float2*)(xsrc + (size_t)s * D + pair * 2);
    uint_t packed = (uint_t)f2bf(v.x) | ((uint_t)f2bf(v.y) << 16);
    __hip_bfloat162 hv;
    __builtin_memcpy(&hv, &packed, 4);
    pk_add((__hip_bfloat162*)(agg + (size_t)d * D) + pair, hv, 0);
    if (pair == 0) atomicAdd(&cnt[d], 1.0f);
}

// Layer-2 scalar aggregation: sum2[dst] += s_pat[src].
__global__ __launch_bounds__(256) void scatter_scalar_kernel(
    const float* __restrict__ sval, const int* __restrict__ src,
    const int* __restrict__ dst, float* __restrict__ sum2, int E)
{
    int e = blockIdx.x * blockDim.x + threadIdx.x;
    if (e < E) atomicAdd(&sum2[dst[e]], sval[src[e]]);
}

__device__ inline bfrag8 ld_cvt8(const float* p) {
    f32x4 v0 = *(const f32x4*)p;
    f32x4 v1 = *(const f32x4*)(p + 4);
    bfrag8 r;
    r[0] = (short)f2bf(v0[0]); r[1] = (short)f2bf(v0[1]);
    r[2] = (short)f2bf(v0[2]); r[3] = (short)f2bf(v0[3]);
    r[4] = (short)f2bf(v1[0]); r[5] = (short)f2bf(v1[1]);
    r[6] = (short)f2bf(v1[2]); r[7] = (short)f2bf(v1[3]);
    return r;
}

// MFMA node transform. One wave = 16 nodes.
//   zL = agg_sum @ Wl (raw bf16 sums); zR = x @ Wr
//   z  = zL * invc + zR + bias ; out = sum_j relu(z)*cvec[j]
//        (+ sum2/cnt + c0 if add_extra)
// A-frag (16x16x32): lane holds A[m=lane&15][k=(lane>>4)*8+jj]
// B-frag: lane holds B[k=(lane>>4)*8+jj][n=lane&15]  (pre-packed by prep)
// C/D:   col(j)=lane&15, row(node)=(lane>>4)*4+reg   (m89/m91-verified)
__global__ __launch_bounds__(256) void transform_mfma_kernel(
    const ushort_t* __restrict__ agg, const float* __restrict__ cnt,
    const float* __restrict__ x_in,
    const ushort_t* __restrict__ fragWl, const ushort_t* __restrict__ fragWr,
    const float* __restrict__ bias, const float* __restrict__ cvec,
    const float* __restrict__ sum2, const float* __restrict__ c0p,
    float* __restrict__ out, int nwaves, int add_extra)
{
    int wid = blockIdx.x * 4 + (threadIdx.x >> 6);
    if (wid >= nwaves) return;
    int l = threadIdx.x & 63;
    int m = l & 15;          // A row (node) for the A-frag this lane feeds
    int q = l >> 4;          // quad
    int nb = wid * 16;
    int row = nb + m;

    // A-frags: Wl path straight from bf16 sums (no conversion), Wr path from f32 x
    const ushort_t* ar = agg + (size_t)row * D;
    bfrag8 a0 = *(const bfrag8*)(ar + q * 8);
    bfrag8 a1 = *(const bfrag8*)(ar + 32 + q * 8);
    const float* xp = x_in + (size_t)row * D;
    bfrag8 x0 = ld_cvt8(xp + q * 8);
    bfrag8 x1 = ld_cvt8(xp + 32 + q * 8);

    // invc for the 4 C-rows (nodes nb+q*4+r) this lane's accumulator holds
    f32x4 c4 = *(const f32x4*)(cnt + nb + q * 4);
    f32x4 invc4;
#pragma unroll
    for (int r = 0; r < 4; r++) invc4[r] = 1.0f / fmaxf(c4[r], 1.0f);

    // per-lane bias/cvec for col j = m at each jt
    float bias_v[8], cvec_v[8];
#pragma unroll
    for (int jt = 0; jt < 8; jt++) {
        bias_v[jt] = bias[jt * 16 + m];
        cvec_v[jt] = cvec[jt * 16 + m];
    }

    f32x4 p = {0.f, 0.f, 0.f, 0.f};
#pragma unroll
    for (int jt = 0; jt < 8; jt++) {
        const bfrag8* bl0 = (const bfrag8*)(fragWl + ((size_t)(jt * 2 + 0) * 64 + l) * 8);
        const bfrag8* bl1 = (const bfrag8*)(fragWl + ((size_t)(jt * 2 + 1) * 64 + l) * 8);
        const bfrag8* br0 = (const bfrag8*)(fragWr + ((size_t)(jt * 2 + 0) * 64 + l) * 8);
        const bfrag8* br1 = (const bfrag8*)(fragWr + ((size_t)(jt * 2 + 1) * 64 + l) * 8);
        f32x4 accl = {0.f, 0.f, 0.f, 0.f};
        f32x4 accr = {0.f, 0.f, 0.f, 0.f};
        accl = __builtin_amdgcn_mfma_f32_16x16x32_bf16(a0, *bl0, accl, 0, 0, 0);
        accl = __builtin_amdgcn_mfma_f32_16x16x32_bf16(a1, *bl1, accl, 0, 0, 0);
        accr = __builtin_amdgcn_mfma_f32_16x16x32_bf16(x0, *br0, accr, 0, 0, 0);
        accr = __builtin_amdgcn_mfma_f32_16x16x32_bf16(x1, *br1, accr, 0, 0, 0);
        float bj = bias_v[jt], cj = cvec_v[jt];
#pragma unroll
        for (int r = 0; r < 4; r++) {
            float z = accl[r] * invc4[r] + accr[r] + bj;
            p[r] += fmaxf(z, 0.f) * cj;
        }
    }
    // sum over the 16 lanes of each quad (j-cols 0..15, same nodes)
#pragma unroll
    for (int off = 1; off < 16; off <<= 1) {
        p[0] += __shfl_xor(p[0], off, 16);
        p[1] += __shfl_xor(p[1], off, 16);
        p[2] += __shfl_xor(p[2], off, 16);
        p[3] += __shfl_xor(p[3], off, 16);
    }
    if (m == 0) {
        int base = nb + q * 4;   // this quad's 4 nodes
        f32x4 o = p;
        if (add_extra) {
            float c0 = c0p[0];
#pragma unroll
            for (int r = 0; r < 4; r++)
                o[r] += sum2[base + r] * invc4[r] + c0;
        }
        *(f32x4*)(out + base) = o;
    }
}

extern "C" void kernel_launch(void* const* d_in, const int* in_sizes, int n_in,
                              void* d_out, int out_size, void* d_ws, size_t ws_size,
                              hipStream_t stream)
{
    const float* x_enc  = (const float*)d_in[0];
    const float* x_pat  = (const float*)d_in[1];
    const int*   src_pe = (const int*)d_in[2];
    const int*   dst_pe = (const int*)d_in[3];
    const int*   src_ep = (const int*)d_in[4];
    const int*   dst_ep = (const int*)d_in[5];
    const float* Wl_pe1 = (const float*)d_in[6];
    const float* Wr_pe1 = (const float*)d_in[7];
    const float* b_pe1  = (const float*)d_in[8];
    const float* Wl_ep1 = (const float*)d_in[9];
    const float* Wr_ep1 = (const float*)d_in[10];
    const float* b_ep1  = (const float*)d_in[11];
    const float* Wl_pe2 = (const float*)d_in[12];
    const float* Wr_pe2 = (const float*)d_in[13];
    const float* b_pe2  = (const float*)d_in[14];
    const float* Wc = (const float*)d_in[18];
    const float* bc = (const float*)d_in[19];

    float* ws  = (float*)d_ws;
    float* out = (float*)d_out;

    hipMemsetAsync(d_ws, 0, (size_t)ZERO_FLOATS * sizeof(float), stream);

    prep_kernel<<<128, 256, 0, stream>>>(Wl_pe1, Wr_pe1, Wl_ep1, Wr_ep1,
                                         Wl_pe2, Wr_pe2, b_pe2, Wc, bc, ws);

    ushort_t* agg_enc = (ushort_t*)(ws + OFF_AGG_ENC);
    ushort_t* agg_pat = (ushort_t*)(ws + OFF_AGG_PAT);

    int sblocks = (int)(((long long)NE * 32 + 255) / 256);
    scatter_kernel<<<sblocks, 256, 0, stream>>>(
        x_enc, src_ep, dst_ep, agg_pat, ws + OFF_CNT_PAT, NE);
    scatter_kernel<<<sblocks, 256, 0, stream>>>(
        x_pat, src_pe, dst_pe, agg_enc, ws + OFF_CNT_ENC, NE);

    const ushort_t* frags = (const ushort_t*)(ws + OFF_FRAGS);

    // patient transform -> s_pat (scalar per patient); Wl_ep1/Wr_ep1, cvec=wl2c
    int pat_waves = N_PAT / 16;   // 6250
    transform_mfma_kernel<<<(pat_waves + 3) / 4, 256, 0, stream>>>(
        agg_pat, ws + OFF_CNT_PAT, x_pat,
        frags + 2 * 8192, frags + 3 * 8192, b_ep1, ws + OFF_WL2C,
        nullptr, nullptr, ws + OFF_SPAT, pat_waves, 0);

    // layer-2 scalar aggregation
    scatter_scalar_kernel<<<(NE + 255) / 256, 256, 0, stream>>>(
        ws + OFF_SPAT, src_pe, dst_pe, ws + OFF_SUM2, NE);

    // encounter transform -> logits; Wl_pe1/Wr_pe1, cvec=wr2c
    int enc_waves = N_ENC / 16;   // 31250
    transform_mfma_kernel<<<(enc_waves + 3) / 4, 256, 0, stream>>>(
        agg_enc, ws + OFF_CNT_ENC, x_enc,
        frags + 0 * 8192, frags + 1 * 8192, b_pe1, ws + OFF_WR2C,
        ws + OFF_SUM2, ws + OFF_C0, out, enc_waves, 1);
}